// Round 3
// baseline (617.504 us; speedup 1.0000x reference)
//
#include <hip/hip_runtime.h>
#include <stdint.h>

// key = (t << 32) | (pos+1); key==0 <=> empty node.
// Lexicographic u64 max == (max t, ties -> max pos).
static __device__ __forceinline__ unsigned long long pack_key(int t, int pos) {
    return ((unsigned long long)(unsigned int)t << 32) | (unsigned int)(pos + 1);
}

__global__ void init_ws_kernel(unsigned long long* __restrict__ ws, int n) {
    int i = blockIdx.x * blockDim.x + threadIdx.x;
    if (i < n) ws[i] = 0ULL;
}

// Single-pass scatter: unconditional u64 atomicMax for every event.
// Round-1 evidence: cutting atomics 266k->130k changed nothing, so atomic
// throughput is not the bottleneck at this scale; the hi/lo filter split's
// second 8MB t/idx stream + extra launch was pure overhead. Memory-side
// device-scope RMWs need no read-filter and no multi-pass visibility dance.
__global__ void __launch_bounds__(256)
scatter_kernel(const int* __restrict__ t, const int* __restrict__ idx,
               unsigned long long* __restrict__ ws, int E) {
    int i0 = (blockIdx.x * blockDim.x + threadIdx.x) * 4;
    if (i0 + 3 < E) {
        int4 tv = *(const int4*)(t + i0);
        int4 iv = *(const int4*)(idx + i0);
        atomicMax(&ws[iv.x], pack_key(tv.x, i0 + 0));
        atomicMax(&ws[iv.y], pack_key(tv.y, i0 + 1));
        atomicMax(&ws[iv.z], pack_key(tv.z, i0 + 2));
        atomicMax(&ws[iv.w], pack_key(tv.w, i0 + 3));
    } else if (i0 < E) {
        for (int i = i0; i < E; ++i)
            atomicMax(&ws[idx[i]], pack_key(t[i], i));
    }
}

// Gather: 32 lanes per node (D=128 floats = 32 float4), 2 nodes per thread
// for MLP=2. Rows are 512B contiguous -> coalesced within each 32-lane group.
// Separate dispatch: kernel-boundary acquire guarantees fresh ws reads.
__global__ void __launch_bounds__(256)
gather_kernel(const unsigned long long* __restrict__ ws,
              const float4* __restrict__ msg,
              float4* __restrict__ out, int N, int half) {
    int gid = blockIdx.x * blockDim.x + threadIdx.x;
    int lane = gid & 31;
    int na = gid >> 5;
    if (na >= half) return;
    int nb = na + half;

    unsigned long long ka = ws[na];
    unsigned long long kb = (nb < N) ? ws[nb] : 0ULL;

    float4 va = make_float4(0.f, 0.f, 0.f, 0.f);
    float4 vb = va;
    if (ka != 0ULL) {
        int pa = (int)(unsigned int)(ka & 0xFFFFFFFFULL) - 1;
        va = msg[(size_t)pa * 32 + lane];
    }
    if (kb != 0ULL) {
        int pb = (int)(unsigned int)(kb & 0xFFFFFFFFULL) - 1;
        vb = msg[(size_t)pb * 32 + lane];
    }
    out[(size_t)na * 32 + lane] = va;
    if (nb < N) out[(size_t)nb * 32 + lane] = vb;
}

extern "C" void kernel_launch(void* const* d_in, const int* in_sizes, int n_in,
                              void* d_out, int out_size, void* d_ws, size_t ws_size,
                              hipStream_t stream) {
    const float* msg = (const float*)d_in[0];
    const int* index = (const int*)d_in[1];
    const int* t     = (const int*)d_in[2];
    const int D = 128;
    const int E = in_sizes[0] / D;
    const int N = out_size / D;

    unsigned long long* ws = (unsigned long long*)d_ws;

    {
        int threads = 256;
        int blocks = (N + threads - 1) / threads;
        init_ws_kernel<<<blocks, threads, 0, stream>>>(ws, N);
    }
    {
        int threads = 256;
        int nthreads = (E + 3) / 4;
        int blocks = (nthreads + threads - 1) / threads;
        scatter_kernel<<<blocks, threads, 0, stream>>>(t, index, ws, E);
    }
    {
        int threads = 256;
        int half = (N + 1) / 2;
        long long total = (long long)half * 32;
        int blocks = (int)((total + threads - 1) / threads);
        gather_kernel<<<blocks, threads, 0, stream>>>(
            ws, (const float4*)msg, (float4*)d_out, N, half);
    }
}